// Round 7
// baseline (323.006 us; speedup 1.0000x reference)
//
#include <hip/hip_runtime.h>

#define S_LEN 2048
#define D_DIM 1024
#define NHEAD 16
#define DH 64
#define BATCH 2
#define NROWS (BATCH * S_LEN)  // 4096
#define QSCALE 0.18033688011112042f  // 0.125 * log2(e): scores land in log2 domain

typedef __attribute__((ext_vector_type(8))) short short8;
typedef __attribute__((ext_vector_type(4))) float f32x4;

static __device__ __forceinline__ unsigned short f2bf(float f) {
    unsigned int u = __builtin_bit_cast(unsigned int, f);
    u += 0x7fffu + ((u >> 16) & 1u);
    return (unsigned short)(u >> 16);
}
static __device__ __forceinline__ float bf2f(unsigned short h) {
    unsigned int u = ((unsigned int)h) << 16;
    return __builtin_bit_cast(float, u);
}
static __device__ __forceinline__ unsigned short f2bf_trunc(float f) {
    return (unsigned short)(__builtin_bit_cast(unsigned int, f) >> 16);
}

// ---------------- fp32 -> bf16 convert (inputs + weights) + fused padding masks --------
__global__ __launch_bounds__(256) void cvt_all_kernel(
    const float* __restrict__ s0, const float* __restrict__ s1, const float* __restrict__ s2,
    const float* __restrict__ w0, const float* __restrict__ w1, const float* __restrict__ w2,
    unsigned short* __restrict__ d0, unsigned short* __restrict__ d1,
    unsigned short* __restrict__ d2, unsigned short* __restrict__ e0,
    unsigned short* __restrict__ e1, unsigned short* __restrict__ e2,
    float* __restrict__ qm, float* __restrict__ km) {
    const int y = blockIdx.y;
    const int row = blockIdx.x;
    const int t = threadIdx.x;
    const float* src;
    unsigned short* dst;
    size_t i;
    if (row < NROWS) {
        src = y == 0 ? s0 : (y == 1 ? s1 : s2);
        dst = y == 0 ? d0 : (y == 1 ? d1 : d2);
        i = (size_t)row * 256 + t;
    } else {
        src = y == 0 ? w0 : (y == 1 ? w1 : w2);
        dst = y == 0 ? e0 : (y == 1 ? e1 : e2);
        i = (size_t)(row - NROWS) * 256 + t;
    }
    float4 v = ((const float4*)src)[i];
    ushort4 o;
    o.x = f2bf(v.x); o.y = f2bf(v.y); o.z = f2bf(v.z); o.w = f2bf(v.w);
    ((ushort4*)dst)[i] = o;
    if (row < NROWS && y < 2) {
        float s = v.x + v.y + v.z + v.w;
        for (int off = 1; off < 64; off <<= 1) s += __shfl_xor(s, off);
        __shared__ float red[4];
        const int w = t >> 6;
        if ((t & 63) == 0) red[w] = s;
        __syncthreads();
        if (t == 0) {
            float tt = red[0] + red[1] + red[2] + red[3];
            if (y == 0)
                qm[row] = (tt != 0.0f) ? 1.0f : 0.0f;
            else
                km[row] = (tt != 0.0f) ? 0.0f : -4294967295.0f;
        }
    }
}

// ---------------- fused QKV projection: O = relu(A @ W^T + b), bf16 MFMA ----------------
// Flat 768-block grid, n-major-mod-8 XCD swizzle: the 8 n-blocks sharing an A-tile get
// linear ids n*96 + (m*3+z), i.e. identical id mod 8 -> same XCD -> A-tile hits L2.
// z==0 (Q): output scaled by QSCALE (attention scale + log2e for exp2 softmax).
__global__ __launch_bounds__(256) void proj_kernel(
    const unsigned short* __restrict__ A0, const unsigned short* __restrict__ A1,
    const unsigned short* __restrict__ A2, const unsigned short* __restrict__ W0,
    const unsigned short* __restrict__ W1, const unsigned short* __restrict__ W2,
    const float* __restrict__ b0, const float* __restrict__ b1, const float* __restrict__ b2,
    unsigned short* __restrict__ O0, unsigned short* __restrict__ O1,
    unsigned short* __restrict__ O2) {
    const int u = blockIdx.x;
    const int n = u / 96;
    const int rem = u % 96;
    const int m = rem / 3;
    const int z = rem % 3;
    const unsigned short* A;
    const unsigned short* W;
    const float* bias;
    unsigned short* O;
    if (z == 0) { A = A0; W = W0; bias = b0; O = O0; }
    else if (z == 1) { A = A1; W = W1; bias = b1; O = O1; }
    else { A = A2; W = W2; bias = b2; O = O2; }

    __shared__ __align__(16) unsigned short Asm[128 * 32];
    __shared__ __align__(16) unsigned short Bsm[128 * 32];

    const int t = threadIdx.x;
    const int w = t >> 6, l = t & 63;
    const int quad = l >> 4, lr = l & 15;
    const int wm = w >> 1, wn = w & 1;
    const int m0 = m * 128, n0 = n * 128;

    f32x4 zero = {0.f, 0.f, 0.f, 0.f};
    f32x4 acc[4][4];
#pragma unroll
    for (int i = 0; i < 4; i++)
#pragma unroll
        for (int j = 0; j < 4; j++) acc[i][j] = zero;

    const int c0 = w * 2, c1 = w * 2 + 1;
    const int ar0 = c0 * 16 + (l >> 2), ar1 = c1 * 16 + (l >> 2);
    const int acol = (l & 3) * 8;

    for (int kt = 0; kt < D_DIM / 32; ++kt) {
        const int k0 = kt * 32;
        __syncthreads();
        __builtin_amdgcn_global_load_lds(
            (const __attribute__((address_space(1))) void*)(A + (size_t)(m0 + ar0) * D_DIM + k0 + acol),
            (__attribute__((address_space(3))) void*)(&Asm[c0 * 512]), 16, 0, 0);
        __builtin_amdgcn_global_load_lds(
            (const __attribute__((address_space(1))) void*)(A + (size_t)(m0 + ar1) * D_DIM + k0 + acol),
            (__attribute__((address_space(3))) void*)(&Asm[c1 * 512]), 16, 0, 0);
        __builtin_amdgcn_global_load_lds(
            (const __attribute__((address_space(1))) void*)(W + (size_t)(n0 + ar0) * D_DIM + k0 + acol),
            (__attribute__((address_space(3))) void*)(&Bsm[c0 * 512]), 16, 0, 0);
        __builtin_amdgcn_global_load_lds(
            (const __attribute__((address_space(1))) void*)(W + (size_t)(n0 + ar1) * D_DIM + k0 + acol),
            (__attribute__((address_space(3))) void*)(&Bsm[c1 * 512]), 16, 0, 0);
        __syncthreads();

        short8 af[4], bf[4];
#pragma unroll
        for (int i = 0; i < 4; i++)
            af[i] = *(const short8*)&Asm[(wm * 64 + i * 16 + lr) * 32 + quad * 8];
#pragma unroll
        for (int j = 0; j < 4; j++)
            bf[j] = *(const short8*)&Bsm[(wn * 64 + j * 16 + lr) * 32 + quad * 8];
#pragma unroll
        for (int i = 0; i < 4; i++)
#pragma unroll
            for (int j = 0; j < 4; j++)
                acc[i][j] = __builtin_amdgcn_mfma_f32_16x16x32_bf16(af[i], bf[j], acc[i][j], 0, 0, 0);
    }

    const float oscale = (z == 0) ? QSCALE : 1.0f;
#pragma unroll
    for (int j = 0; j < 4; j++) {
        const int gn = n0 + wn * 64 + j * 16 + lr;
        const float bj = bias[gn];
#pragma unroll
        for (int i = 0; i < 4; i++) {
            const int gmb = m0 + wm * 64 + i * 16 + quad * 4;
#pragma unroll
            for (int r = 0; r < 4; r++) {
                float v = fmaxf(acc[i][j][r] + bj, 0.f) * oscale;
                O[(size_t)(gmb + r) * D_DIM + gn] = f2bf(v);
            }
        }
    }
}

// ---------------- V transpose: (B,S,D) bf16 -> (B,H,dh,S) bf16 (coalesced both ways) ----
__global__ __launch_bounds__(256) void transpose_v(const unsigned short* __restrict__ Vb,
                                                   unsigned short* __restrict__ Vt) {
    __shared__ unsigned short tile[64][65];
    const int s0 = blockIdx.x * 64, h = blockIdx.y, b = blockIdx.z;
    const int t = threadIdx.x;
#pragma unroll
    for (int p = 0; p < 16; p++) {
        int idx = p * 256 + t;
        int si = idx >> 6, ni = idx & 63;
        tile[si][ni] = Vb[(size_t)(b * S_LEN + s0 + si) * D_DIM + h * DH + ni];
    }
    __syncthreads();
#pragma unroll
    for (int p = 0; p < 16; p++) {
        int idx = p * 256 + t;
        int ni = idx >> 6, si = idx & 63;
        Vt[((size_t)(b * NHEAD + h) * DH + ni) * S_LEN + s0 + si] = tile[si][ni];
    }
}

// ---------------- flash attention: 128-row q-tiles, 32 q-rows/wave, exp2 softmax --------
// grid (32, H, B) = 1024 blocks = exactly 4/CU (LDS 40960 B), one co-resident round.
// Wave = two 16-row subtiles: K/V LDS fragments read ONCE, reused for both (halves the
// LDS-pipe traffic per unit work vs r6 — the measured binding pipe).
// Split-K: T = 2(qt+1) 64-key tiles, ns = ceil(T/11); max 11 tiles/block.
// K prefetch issued AFTER B2 so B2's vmcnt(0) drain waits only on V.
__global__ __launch_bounds__(256, 4) void attn_kernel(
    const unsigned short* __restrict__ Qb, const unsigned short* __restrict__ Kb,
    const unsigned short* __restrict__ Vt, const float* __restrict__ km_pen,
    unsigned short* __restrict__ oP0, unsigned short* __restrict__ oP1,
    unsigned short* __restrict__ oP2, float* __restrict__ lP) {
    __shared__ __align__(16) unsigned short Ks[2][64 * 64];
    __shared__ __align__(16) unsigned short Vs[64 * 64];
    __shared__ __align__(16) unsigned short Ps[4][32 * 64];

    const int w = threadIdx.x >> 6, l = threadIdx.x & 63;
    const int quad = l >> 4, lr = l & 15;
    const int h = blockIdx.y, b = blockIdx.z;
    const float NEGF = -4294967295.0f;

    // ---- work assignment (LPT: longest first) ----
    int qt, sp, ns;
    const int x = blockIdx.x;
    if (x < 15) { qt = 15 - x / 3; sp = x % 3; ns = 3; }
    else if (x < 27) { int y = x - 15; qt = 10 - y / 2; sp = y % 2; ns = 2; }
    else { qt = 31 - x; sp = 0; ns = 1; }
    const int T = 2 * (qt + 1);
    const int lo = sp * T / ns, hi = (sp + 1) * T / ns;

    const int q0 = qt * 128;
    const int qb0 = q0 + w * 32;   // subtile 0 rows
    const int qb1 = qb0 + 16;      // subtile 1 rows

    const int cA = w * 128 + l;
    const int cB = w * 128 + 64 + l;
    const int keyA = cA >> 3, cbA = (cA & 7) ^ (keyA & 7);
    const int keyB = cB >> 3, cbB = (cB & 7) ^ (keyB & 7);
    const unsigned short* Krow = Kb + (size_t)b * S_LEN * D_DIM + h * DH;
    const unsigned short* Vrow = Vt + (size_t)(b * NHEAD + h) * DH * S_LEN;

    const unsigned short* kSA = Krow + (size_t)(lo * 64 + keyA) * D_DIM + cbA * 8;
    const unsigned short* kSB = Krow + (size_t)(lo * 64 + keyB) * D_DIM + cbB * 8;
    const unsigned short* vSA = Vrow + (size_t)keyA * S_LEN + lo * 64 + cbA * 8;
    const unsigned short* vSB = Vrow + (size_t)keyB * S_LEN + lo * 64 + cbB * 8;
    const float* kmp = km_pen + b * S_LEN + lo * 64 + lr;

    unsigned short* const kD0 = &Ks[0][(w * 128) * 8];
    unsigned short* const kD1 = &Ks[0][(w * 128 + 64) * 8];
    unsigned short* const kE0 = &Ks[1][(w * 128) * 8];
    unsigned short* const kE1 = &Ks[1][(w * 128 + 64) * 8];
    unsigned short* const vD0 = &Vs[(w * 128) * 8];
    unsigned short* const vD1 = &Vs[(w * 128 + 64) * 8];

    const unsigned short* qp0 = Qb + (size_t)(b * S_LEN + qb0 + lr) * D_DIM + h * DH + quad * 8;
    const unsigned short* qp1 = Qb + (size_t)(b * S_LEN + qb1 + lr) * D_DIM + h * DH + quad * 8;
    const short8 qf00 = *(const short8*)(qp0);
    const short8 qf01 = *(const short8*)(qp0 + 32);
    const short8 qf10 = *(const short8*)(qp1);
    const short8 qf11 = *(const short8*)(qp1 + 32);

    f32x4 zero = {0.f, 0.f, 0.f, 0.f};
    f32x4 o[2][4];
#pragma unroll
    for (int s = 0; s < 2; s++)
#pragma unroll
        for (int j = 0; j < 4; j++) o[s][j] = zero;
    float l_part[2][4] = {{0.f, 0.f, 0.f, 0.f}, {0.f, 0.f, 0.f, 0.f}};

    unsigned short* myP = Ps[w];
    const int swz0 = quad ^ (lr & 7);
    const int swz1 = (quad + 4) ^ (lr & 7);

#define GLDS(src, dst)                                                                  \
    __builtin_amdgcn_global_load_lds((const __attribute__((address_space(1))) void*)(src), \
                                     (__attribute__((address_space(3))) void*)(dst), 16, 0, 0)

    // stage K(lo) into Ks[0]
    GLDS(kSA, kD0);
    GLDS(kSB, kD1);
    kSA += 64 * D_DIM;
    kSB += 64 * D_DIM;

    for (int kt = lo; kt < hi; ++kt) {
        const int cur = (kt - lo) & 1;
        __syncthreads();  // B1: K(kt) staged (drain), prev PV reads of Vs done
        GLDS(vSA, vD0);   // V(kt): lands during QK+softmax, drained at B2
        GLDS(vSB, vD1);
        vSA += 64;
        vSB += 64;

        float kmv[4];
#pragma unroll
        for (int nf = 0; nf < 4; nf++) kmv[nf] = kmp[nf * 16];
        kmp += 64;

        // ---- scores (log2 domain): 32q x 64k, K fragments read once ----
        f32x4 sc0[4], sc1[4];
#pragma unroll
        for (int nf = 0; nf < 4; nf++) {
            const int key = nf * 16 + lr;
            const short8 kf0 = *(const short8*)&Ks[cur][(key * 8 + swz0) * 8];
            const short8 kf1 = *(const short8*)&Ks[cur][(key * 8 + swz1) * 8];
            f32x4 z0 = zero, z1 = zero;
            z0 = __builtin_amdgcn_mfma_f32_16x16x32_bf16(qf00, kf0, z0, 0, 0, 0);
            z0 = __builtin_amdgcn_mfma_f32_16x16x32_bf16(qf01, kf1, z0, 0, 0, 0);
            z1 = __builtin_amdgcn_mfma_f32_16x16x32_bf16(qf10, kf0, z1, 0, 0, 0);
            z1 = __builtin_amdgcn_mfma_f32_16x16x32_bf16(qf11, kf1, z1, 0, 0, 0);
            sc0[nf] = z0;
            sc1[nf] = z1;
        }

        // ---- softmax per subtile: bare exp2; causal branch is wave-uniform ----
        const int k0 = kt * 64;
#pragma unroll
        for (int s = 0; s < 2; s++) {
            const int qbs = s ? qb1 : qb0;
            const f32x4* sc = s ? sc1 : sc0;
            float* lp = l_part[s];
            if (k0 + 63 > qbs) {  // diagonal/above: per-element causal mask
#pragma unroll
                for (int r = 0; r < 4; r++) {
                    const int row = s * 16 + quad * 4 + r;
                    const int q = qbs + quad * 4 + r;
                    const float v0 = (k0 + lr <= q) ? sc[0][r] + kmv[0] : NEGF;
                    const float v1 = (k0 + 16 + lr <= q) ? sc[1][r] + kmv[1] : NEGF;
                    const float v2 = (k0 + 32 + lr <= q) ? sc[2][r] + kmv[2] : NEGF;
                    const float v3 = (k0 + 48 + lr <= q) ? sc[3][r] + kmv[3] : NEGF;
                    const float e0 = exp2f(v0);
                    const float e1 = exp2f(v1);
                    const float e2 = exp2f(v2);
                    const float e3 = exp2f(v3);
                    lp[r] += (e0 + e1) + (e2 + e3);
                    const int rb = (row & 7);
                    const int base = row * 64 + (lr & 7);
                    myP[base + (((0 + (lr >> 3)) ^ rb) << 3)] = f2bf_trunc(e0);
                    myP[base + (((2 + (lr >> 3)) ^ rb) << 3)] = f2bf_trunc(e1);
                    myP[base + (((4 + (lr >> 3)) ^ rb) << 3)] = f2bf_trunc(e2);
                    myP[base + (((6 + (lr >> 3)) ^ rb) << 3)] = f2bf_trunc(e3);
                }
            } else {
#pragma unroll
                for (int r = 0; r < 4; r++) {
                    const int row = s * 16 + quad * 4 + r;
                    const float e0 = exp2f(sc[0][r] + kmv[0]);
                    const float e1 = exp2f(sc[1][r] + kmv[1]);
                    const float e2 = exp2f(sc[2][r] + kmv[2]);
                    const float e3 = exp2f(sc[3][r] + kmv[3]);
                    lp[r] += (e0 + e1) + (e2 + e3);
                    const int rb = (row & 7);
                    const int base = row * 64 + (lr & 7);
                    myP[base + (((0 + (lr >> 3)) ^ rb) << 3)] = f2bf_trunc(e0);
                    myP[base + (((2 + (lr >> 3)) ^ rb) << 3)] = f2bf_trunc(e1);
                    myP[base + (((4 + (lr >> 3)) ^ rb) << 3)] = f2bf_trunc(e2);
                    myP[base + (((6 + (lr >> 3)) ^ rb) << 3)] = f2bf_trunc(e3);
                }
            }
        }

        __syncthreads();  // B2: V(kt) drained (K(kt+1) not yet issued -> no false stall)

        if (kt + 1 < hi) {  // prefetch K(kt+1): lands during PV, drained at next B1
            if (cur) { GLDS(kSA, kD0); GLDS(kSB, kD1); }
            else     { GLDS(kSA, kE0); GLDS(kSB, kE1); }
            kSA += 64 * D_DIM;
            kSB += 64 * D_DIM;
        }

        // ---- PV: V fragments read once, used by both subtiles ----
#pragma unroll
        for (int cs = 0; cs < 2; cs++) {
            const int swz = cs ? swz1 : swz0;
            const int poff = (((cs * 4 + quad) ^ (lr & 7)) << 3);
            const short8 pf0 = *(const short8*)&myP[lr * 64 + poff];
            const short8 pf1 = *(const short8*)&myP[(16 + lr) * 64 + poff];
#pragma unroll
            for (int j = 0; j < 4; j++) {
                const short8 vfj = *(const short8*)&Vs[((j * 16 + lr) * 8 + swz) * 8];
                o[0][j] = __builtin_amdgcn_mfma_f32_16x16x32_bf16(pf0, vfj, o[0][j], 0, 0, 0);
                o[1][j] = __builtin_amdgcn_mfma_f32_16x16x32_bf16(pf1, vfj, o[1][j], 0, 0, 0);
            }
        }
    }
#undef GLDS

    // ---- epilogue: bf16 O-partials + fp32 l-partials ----
    unsigned short* oP = (sp == 0) ? oP0 : ((sp == 1) ? oP1 : oP2);
#pragma unroll
    for (int s = 0; s < 2; s++) {
        const int qbs = s ? qb1 : qb0;
#pragma unroll
        for (int r = 0; r < 4; r++) {
            float ls = l_part[s][r];
            ls += __shfl_xor(ls, 1);
            ls += __shfl_xor(ls, 2);
            ls += __shfl_xor(ls, 4);
            ls += __shfl_xor(ls, 8);
            const int q = qbs + quad * 4 + r;
            if (lr == 0) lP[sp * (BATCH * NHEAD * S_LEN) + (b * NHEAD + h) * S_LEN + q] = ls;
#pragma unroll
            for (int j = 0; j < 4; j++) {
                oP[(size_t)(b * S_LEN + q) * D_DIM + h * DH + j * 16 + lr] = f2bf(o[s][j][r]);
            }
        }
    }
}

// ---------------- residual + layernorm + split-K combine (up to 3 partials) ------------
__global__ __launch_bounds__(256) void ln_kernel(
    const unsigned short* __restrict__ oP0, const unsigned short* __restrict__ oP1,
    const unsigned short* __restrict__ oP2, const float* __restrict__ lP,
    const float* __restrict__ qmask, const float* __restrict__ queries,
    const float* __restrict__ gamma, const float* __restrict__ beta,
    float* __restrict__ out) {
    const int row = blockIdx.x;
    const int t = threadIdx.x;
    const int b = row >> 11, q = row & 2047;
    const int qt = q >> 7;  // 128-row q-tiles
    const int ns = (qt <= 4) ? 1 : ((qt <= 10) ? 2 : 3);
    const int h = t >> 4;
    const int lidx = (b * NHEAD + h) * S_LEN + q;
    const int LSTRIDE = BATCH * NHEAD * S_LEN;

    float ls = lP[lidx];
    const size_t ri = (size_t)row * 256 + t;
    const ushort4 a0 = ((const ushort4*)oP0)[ri];
    float sx = bf2f(a0.x), sy = bf2f(a0.y), sz = bf2f(a0.z), sw = bf2f(a0.w);
    if (ns > 1) {
        ls += lP[LSTRIDE + lidx];
        const ushort4 a1 = ((const ushort4*)oP1)[ri];
        sx += bf2f(a1.x); sy += bf2f(a1.y); sz += bf2f(a1.z); sw += bf2f(a1.w);
    }
    if (ns > 2) {
        ls += lP[2 * LSTRIDE + lidx];
        const ushort4 a2 = ((const ushort4*)oP2)[ri];
        sx += bf2f(a2.x); sy += bf2f(a2.y); sz += bf2f(a2.z); sw += bf2f(a2.w);
    }
    const float qmr = qmask[row];
    const float inv0 = (ls > 0.f) ? qmr / ls : 0.f;

    const float4 qv = ((const float4*)(queries + (size_t)row * D_DIM))[t];
    float4 x;
    x.x = sx * inv0 + qv.x;
    x.y = sy * inv0 + qv.y;
    x.z = sz * inv0 + qv.z;
    x.w = sw * inv0 + qv.w;

    float s = x.x + x.y + x.z + x.w;
    float sq = x.x * x.x + x.y * x.y + x.z * x.z + x.w * x.w;
    for (int o = 1; o < 64; o <<= 1) { s += __shfl_xor(s, o); sq += __shfl_xor(sq, o); }
    __shared__ float rs[4], rq[4];
    const int w = t >> 6;
    if ((t & 63) == 0) { rs[w] = s; rq[w] = sq; }
    __syncthreads();
    s = rs[0] + rs[1] + rs[2] + rs[3];
    sq = rq[0] + rq[1] + rq[2] + rq[3];
    const float mean = s * (1.0f / 1024.0f);
    float var = (sq - s * mean) * (1.0f / 1023.0f);
    var = fmaxf(var, 0.f);
    const float inv = 1.0f / (sqrtf(var) + 1e-8f);
    const float4 g = ((const float4*)gamma)[t];
    const float4 bb = ((const float4*)beta)[t];
    float4 y;
    y.x = g.x * (x.x - mean) * inv + bb.x;
    y.y = g.y * (x.y - mean) * inv + bb.y;
    y.z = g.z * (x.z - mean) * inv + bb.z;
    y.w = g.w * (x.w - mean) * inv + bb.w;
    ((float4*)(out + (size_t)row * D_DIM))[t] = y;
}

extern "C" void kernel_launch(void* const* d_in, const int* in_sizes, int n_in, void* d_out,
                              int out_size, void* d_ws, size_t ws_size, hipStream_t stream) {
    const float* queries = (const float*)d_in[0];
    const float* keys = (const float*)d_in[1];
    const float* values = (const float*)d_in[2];
    const float* Wq = (const float*)d_in[3];
    const float* bq = (const float*)d_in[4];
    const float* Wk = (const float*)d_in[5];
    const float* bk = (const float*)d_in[6];
    const float* Wv = (const float*)d_in[7];
    const float* bv = (const float*)d_in[8];
    const float* gamma = (const float*)d_in[9];
    const float* beta = (const float*)d_in[10];
    float* out = (float*)d_out;
    char* ws = (char*)d_ws;

    const size_t MB = 1048576;
    unsigned short* qin = (unsigned short*)(ws + 0);
    unsigned short* kin = (unsigned short*)(ws + 8 * MB);
    unsigned short* vin = (unsigned short*)(ws + 16 * MB);
    unsigned short* wqb = (unsigned short*)(ws + 24 * MB);
    unsigned short* wkb = (unsigned short*)(ws + 26 * MB);
    unsigned short* wvb = (unsigned short*)(ws + 28 * MB);
    unsigned short* Qb = (unsigned short*)(ws + 30 * MB);
    unsigned short* Kb = (unsigned short*)(ws + 38 * MB);
    unsigned short* Vb = (unsigned short*)(ws + 46 * MB);
    unsigned short* Vt = (unsigned short*)(ws + 0);          // aliases qin (dead after proj)
    unsigned short* oP0 = (unsigned short*)(ws + 16 * MB);   // aliases vin (dead)
    unsigned short* oP1 = (unsigned short*)(ws + 46 * MB);   // aliases Vb (dead after transpose)
    unsigned short* oP2 = (unsigned short*)(ws + 8 * MB);    // aliases kin (dead)
    float* qm = (float*)(ws + 54 * MB);
    float* km = (float*)(ws + 54 * MB + 16384);
    float* lP = (float*)(ws + 54 * MB + 32768);  // 3 x 65536 fp32 = 768KB

    cvt_all_kernel<<<dim3(NROWS + D_DIM, 3), 256, 0, stream>>>(
        queries, keys, values, Wq, Wk, Wv, qin, kin, vin, wqb, wkb, wvb, qm, km);

    proj_kernel<<<768, 256, 0, stream>>>(
        qin, kin, vin, wqb, wkb, wvb, bq, bk, bv, Qb, Kb, Vb);

    transpose_v<<<dim3(S_LEN / 64, NHEAD, BATCH), 256, 0, stream>>>(Vb, Vt);

    attn_kernel<<<dim3(32, NHEAD, BATCH), 256, 0, stream>>>(Qb, Kb, Vt, km, oP0, oP1, oP2, lP);

    ln_kernel<<<NROWS, 256, 0, stream>>>(oP0, oP1, oP2, lP, qm, queries, gamma, beta, out);
}

// Round 8
// 220.725 us; speedup vs baseline: 1.4634x; 1.4634x over previous
//
#include <hip/hip_runtime.h>

#define S_LEN 2048
#define D_DIM 1024
#define NHEAD 16
#define DH 64
#define BATCH 2
#define NROWS (BATCH * S_LEN)  // 4096
#define QSCALE 0.18033688011112042f  // 0.125 * log2(e): scores land in log2 domain

typedef __attribute__((ext_vector_type(8))) short short8;
typedef __attribute__((ext_vector_type(4))) float f32x4;

static __device__ __forceinline__ unsigned short f2bf(float f) {
    unsigned int u = __builtin_bit_cast(unsigned int, f);
    u += 0x7fffu + ((u >> 16) & 1u);
    return (unsigned short)(u >> 16);
}
static __device__ __forceinline__ float bf2f(unsigned short h) {
    unsigned int u = ((unsigned int)h) << 16;
    return __builtin_bit_cast(float, u);
}
static __device__ __forceinline__ unsigned short f2bf_trunc(float f) {
    return (unsigned short)(__builtin_bit_cast(unsigned int, f) >> 16);
}

// ---------------- fp32 -> bf16 convert (inputs + weights) + fused padding masks --------
__global__ __launch_bounds__(256) void cvt_all_kernel(
    const float* __restrict__ s0, const float* __restrict__ s1, const float* __restrict__ s2,
    const float* __restrict__ w0, const float* __restrict__ w1, const float* __restrict__ w2,
    unsigned short* __restrict__ d0, unsigned short* __restrict__ d1,
    unsigned short* __restrict__ d2, unsigned short* __restrict__ e0,
    unsigned short* __restrict__ e1, unsigned short* __restrict__ e2,
    float* __restrict__ qm, float* __restrict__ km) {
    const int y = blockIdx.y;
    const int row = blockIdx.x;
    const int t = threadIdx.x;
    const float* src;
    unsigned short* dst;
    size_t i;
    if (row < NROWS) {
        src = y == 0 ? s0 : (y == 1 ? s1 : s2);
        dst = y == 0 ? d0 : (y == 1 ? d1 : d2);
        i = (size_t)row * 256 + t;
    } else {
        src = y == 0 ? w0 : (y == 1 ? w1 : w2);
        dst = y == 0 ? e0 : (y == 1 ? e1 : e2);
        i = (size_t)(row - NROWS) * 256 + t;
    }
    float4 v = ((const float4*)src)[i];
    ushort4 o;
    o.x = f2bf(v.x); o.y = f2bf(v.y); o.z = f2bf(v.z); o.w = f2bf(v.w);
    ((ushort4*)dst)[i] = o;
    if (row < NROWS && y < 2) {
        float s = v.x + v.y + v.z + v.w;
        for (int off = 1; off < 64; off <<= 1) s += __shfl_xor(s, off);
        __shared__ float red[4];
        const int w = t >> 6;
        if ((t & 63) == 0) red[w] = s;
        __syncthreads();
        if (t == 0) {
            float tt = red[0] + red[1] + red[2] + red[3];
            if (y == 0)
                qm[row] = (tt != 0.0f) ? 1.0f : 0.0f;
            else
                km[row] = (tt != 0.0f) ? 0.0f : -4294967295.0f;
        }
    }
}

// ---------------- fused QKV projection: O = relu(A @ W^T + b), bf16 MFMA ----------------
// Flat 768-block grid, n-major-mod-8 XCD swizzle. z==0 (Q): output scaled by QSCALE.
__global__ __launch_bounds__(256) void proj_kernel(
    const unsigned short* __restrict__ A0, const unsigned short* __restrict__ A1,
    const unsigned short* __restrict__ A2, const unsigned short* __restrict__ W0,
    const unsigned short* __restrict__ W1, const unsigned short* __restrict__ W2,
    const float* __restrict__ b0, const float* __restrict__ b1, const float* __restrict__ b2,
    unsigned short* __restrict__ O0, unsigned short* __restrict__ O1,
    unsigned short* __restrict__ O2) {
    const int u = blockIdx.x;
    const int n = u / 96;
    const int rem = u % 96;
    const int m = rem / 3;
    const int z = rem % 3;
    const unsigned short* A;
    const unsigned short* W;
    const float* bias;
    unsigned short* O;
    if (z == 0) { A = A0; W = W0; bias = b0; O = O0; }
    else if (z == 1) { A = A1; W = W1; bias = b1; O = O1; }
    else { A = A2; W = W2; bias = b2; O = O2; }

    __shared__ __align__(16) unsigned short Asm[128 * 32];
    __shared__ __align__(16) unsigned short Bsm[128 * 32];

    const int t = threadIdx.x;
    const int w = t >> 6, l = t & 63;
    const int quad = l >> 4, lr = l & 15;
    const int wm = w >> 1, wn = w & 1;
    const int m0 = m * 128, n0 = n * 128;

    f32x4 zero = {0.f, 0.f, 0.f, 0.f};
    f32x4 acc[4][4];
#pragma unroll
    for (int i = 0; i < 4; i++)
#pragma unroll
        for (int j = 0; j < 4; j++) acc[i][j] = zero;

    const int c0 = w * 2, c1 = w * 2 + 1;
    const int ar0 = c0 * 16 + (l >> 2), ar1 = c1 * 16 + (l >> 2);
    const int acol = (l & 3) * 8;

    for (int kt = 0; kt < D_DIM / 32; ++kt) {
        const int k0 = kt * 32;
        __syncthreads();
        __builtin_amdgcn_global_load_lds(
            (const __attribute__((address_space(1))) void*)(A + (size_t)(m0 + ar0) * D_DIM + k0 + acol),
            (__attribute__((address_space(3))) void*)(&Asm[c0 * 512]), 16, 0, 0);
        __builtin_amdgcn_global_load_lds(
            (const __attribute__((address_space(1))) void*)(A + (size_t)(m0 + ar1) * D_DIM + k0 + acol),
            (__attribute__((address_space(3))) void*)(&Asm[c1 * 512]), 16, 0, 0);
        __builtin_amdgcn_global_load_lds(
            (const __attribute__((address_space(1))) void*)(W + (size_t)(n0 + ar0) * D_DIM + k0 + acol),
            (__attribute__((address_space(3))) void*)(&Bsm[c0 * 512]), 16, 0, 0);
        __builtin_amdgcn_global_load_lds(
            (const __attribute__((address_space(1))) void*)(W + (size_t)(n0 + ar1) * D_DIM + k0 + acol),
            (__attribute__((address_space(3))) void*)(&Bsm[c1 * 512]), 16, 0, 0);
        __syncthreads();

        short8 af[4], bf[4];
#pragma unroll
        for (int i = 0; i < 4; i++)
            af[i] = *(const short8*)&Asm[(wm * 64 + i * 16 + lr) * 32 + quad * 8];
#pragma unroll
        for (int j = 0; j < 4; j++)
            bf[j] = *(const short8*)&Bsm[(wn * 64 + j * 16 + lr) * 32 + quad * 8];
#pragma unroll
        for (int i = 0; i < 4; i++)
#pragma unroll
            for (int j = 0; j < 4; j++)
                acc[i][j] = __builtin_amdgcn_mfma_f32_16x16x32_bf16(af[i], bf[j], acc[i][j], 0, 0, 0);
    }

    const float oscale = (z == 0) ? QSCALE : 1.0f;
#pragma unroll
    for (int j = 0; j < 4; j++) {
        const int gn = n0 + wn * 64 + j * 16 + lr;
        const float bj = bias[gn];
#pragma unroll
        for (int i = 0; i < 4; i++) {
            const int gmb = m0 + wm * 64 + i * 16 + quad * 4;
#pragma unroll
            for (int r = 0; r < 4; r++) {
                float v = fmaxf(acc[i][j][r] + bj, 0.f) * oscale;
                O[(size_t)(gmb + r) * D_DIM + gn] = f2bf(v);
            }
        }
    }
}

// ---------------- V transpose: (B,S,D) bf16 -> (B,H,dh,S) bf16 (coalesced both ways) ----
__global__ __launch_bounds__(256) void transpose_v(const unsigned short* __restrict__ Vb,
                                                   unsigned short* __restrict__ Vt) {
    __shared__ unsigned short tile[64][65];
    const int s0 = blockIdx.x * 64, h = blockIdx.y, b = blockIdx.z;
    const int t = threadIdx.x;
#pragma unroll
    for (int p = 0; p < 16; p++) {
        int idx = p * 256 + t;
        int si = idx >> 6, ni = idx & 63;
        tile[si][ni] = Vb[(size_t)(b * S_LEN + s0 + si) * D_DIM + h * DH + ni];
    }
    __syncthreads();
#pragma unroll
    for (int p = 0; p < 16; p++) {
        int idx = p * 256 + t;
        int ni = idx >> 6, si = idx & 63;
        Vt[((size_t)(b * NHEAD + h) * DH + ni) * S_LEN + s0 + si] = tile[si][ni];
    }
}

// ---------------- flash attention: 128-row q-tiles, per-nf fused softmax ----------------
// grid (32, H, B) = 1024 blocks = 4/CU (LDS 40960 B). Wave = two 16-row subtiles sharing
// K/V LDS fragments (halves LDS-pipe traffic per work — R6's binding pipe).
// SPILL FIX vs R7: scores are consumed per 16-column block (z0,z1 transient, 8 regs)
// instead of sc0[4]+sc1[4] (64 regs live across softmax). No forced waves/EU bound.
__global__ __launch_bounds__(256) void attn_kernel(
    const unsigned short* __restrict__ Qb, const unsigned short* __restrict__ Kb,
    const unsigned short* __restrict__ Vt, const float* __restrict__ km_pen,
    unsigned short* __restrict__ oP0, unsigned short* __restrict__ oP1,
    unsigned short* __restrict__ oP2, float* __restrict__ lP) {
    __shared__ __align__(16) unsigned short Ks[2][64 * 64];
    __shared__ __align__(16) unsigned short Vs[64 * 64];
    __shared__ __align__(16) unsigned short Ps[4][32 * 64];

    const int w = threadIdx.x >> 6, l = threadIdx.x & 63;
    const int quad = l >> 4, lr = l & 15;
    const int h = blockIdx.y, b = blockIdx.z;
    const float NEGF = -4294967295.0f;

    // ---- work assignment (LPT: longest first) ----
    int qt, sp, ns;
    const int x = blockIdx.x;
    if (x < 15) { qt = 15 - x / 3; sp = x % 3; ns = 3; }
    else if (x < 27) { int y = x - 15; qt = 10 - y / 2; sp = y % 2; ns = 2; }
    else { qt = 31 - x; sp = 0; ns = 1; }
    const int T = 2 * (qt + 1);
    const int lo = sp * T / ns, hi = (sp + 1) * T / ns;

    const int q0 = qt * 128;
    const int qb0 = q0 + w * 32;   // subtile 0 rows
    const int qb1 = qb0 + 16;      // subtile 1 rows

    const int cA = w * 128 + l;
    const int cB = w * 128 + 64 + l;
    const int keyA = cA >> 3, cbA = (cA & 7) ^ (keyA & 7);
    const int keyB = cB >> 3, cbB = (cB & 7) ^ (keyB & 7);
    const unsigned short* Krow = Kb + (size_t)b * S_LEN * D_DIM + h * DH;
    const unsigned short* Vrow = Vt + (size_t)(b * NHEAD + h) * DH * S_LEN;

    const unsigned short* kSA = Krow + (size_t)(lo * 64 + keyA) * D_DIM + cbA * 8;
    const unsigned short* kSB = Krow + (size_t)(lo * 64 + keyB) * D_DIM + cbB * 8;
    const unsigned short* vSA = Vrow + (size_t)keyA * S_LEN + lo * 64 + cbA * 8;
    const unsigned short* vSB = Vrow + (size_t)keyB * S_LEN + lo * 64 + cbB * 8;
    const float* kmp = km_pen + b * S_LEN + lo * 64 + lr;

    unsigned short* const kD0 = &Ks[0][(w * 128) * 8];
    unsigned short* const kD1 = &Ks[0][(w * 128 + 64) * 8];
    unsigned short* const kE0 = &Ks[1][(w * 128) * 8];
    unsigned short* const kE1 = &Ks[1][(w * 128 + 64) * 8];
    unsigned short* const vD0 = &Vs[(w * 128) * 8];
    unsigned short* const vD1 = &Vs[(w * 128 + 64) * 8];

    const unsigned short* qp0 = Qb + (size_t)(b * S_LEN + qb0 + lr) * D_DIM + h * DH + quad * 8;
    const unsigned short* qp1 = Qb + (size_t)(b * S_LEN + qb1 + lr) * D_DIM + h * DH + quad * 8;
    const short8 qf00 = *(const short8*)(qp0);
    const short8 qf01 = *(const short8*)(qp0 + 32);
    const short8 qf10 = *(const short8*)(qp1);
    const short8 qf11 = *(const short8*)(qp1 + 32);

    f32x4 zero = {0.f, 0.f, 0.f, 0.f};
    f32x4 o[2][4];
#pragma unroll
    for (int s = 0; s < 2; s++)
#pragma unroll
        for (int j = 0; j < 4; j++) o[s][j] = zero;
    float l_part[2][4] = {{0.f, 0.f, 0.f, 0.f}, {0.f, 0.f, 0.f, 0.f}};

    unsigned short* myP = Ps[w];
    const int swz0 = quad ^ (lr & 7);
    const int swz1 = (quad + 4) ^ (lr & 7);
    const int lr7 = lr & 7, lrh = lr >> 3;

#define GLDS(src, dst)                                                                  \
    __builtin_amdgcn_global_load_lds((const __attribute__((address_space(1))) void*)(src), \
                                     (__attribute__((address_space(3))) void*)(dst), 16, 0, 0)

    // stage K(lo) into Ks[0]
    GLDS(kSA, kD0);
    GLDS(kSB, kD1);
    kSA += 64 * D_DIM;
    kSB += 64 * D_DIM;

    for (int kt = lo; kt < hi; ++kt) {
        const int cur = (kt - lo) & 1;
        __syncthreads();  // B1: K(kt) staged (drain), prev PV reads of Vs/Ps done
        GLDS(vSA, vD0);   // V(kt): lands during QK+softmax, drained at B2
        GLDS(vSB, vD1);
        vSA += 64;
        vSB += 64;

        float kmv[4];
#pragma unroll
        for (int nf = 0; nf < 4; nf++) kmv[nf] = kmp[nf * 16];
        kmp += 64;

        const int k0 = kt * 64;
        const bool diag0 = (k0 + 63 > qb0);
        const bool diag1 = (k0 + 63 > qb1);

        // ---- per 16-col block: 4 MFMAs then immediate softmax (z transient) ----
#pragma unroll
        for (int nf = 0; nf < 4; nf++) {
            const int key = nf * 16 + lr;
            const short8 kf0 = *(const short8*)&Ks[cur][(key * 8 + swz0) * 8];
            const short8 kf1 = *(const short8*)&Ks[cur][(key * 8 + swz1) * 8];
            f32x4 z0 = zero, z1 = zero;
            z0 = __builtin_amdgcn_mfma_f32_16x16x32_bf16(qf00, kf0, z0, 0, 0, 0);
            z0 = __builtin_amdgcn_mfma_f32_16x16x32_bf16(qf01, kf1, z0, 0, 0, 0);
            z1 = __builtin_amdgcn_mfma_f32_16x16x32_bf16(qf10, kf0, z1, 0, 0, 0);
            z1 = __builtin_amdgcn_mfma_f32_16x16x32_bf16(qf11, kf1, z1, 0, 0, 0);
            const float kmc = kmv[nf];
            const int kcol = k0 + key;
            // subtile 0
            if (diag0) {
#pragma unroll
                for (int r = 0; r < 4; r++) {
                    const int row = quad * 4 + r;
                    const float v = (kcol <= qb0 + row) ? z0[r] + kmc : NEGF;
                    const float e = exp2f(v);
                    l_part[0][r] += e;
                    myP[row * 64 + lr7 + (((nf * 2 + lrh) ^ (row & 7)) << 3)] = f2bf_trunc(e);
                }
            } else {
#pragma unroll
                for (int r = 0; r < 4; r++) {
                    const int row = quad * 4 + r;
                    const float e = exp2f(z0[r] + kmc);
                    l_part[0][r] += e;
                    myP[row * 64 + lr7 + (((nf * 2 + lrh) ^ (row & 7)) << 3)] = f2bf_trunc(e);
                }
            }
            // subtile 1
            if (diag1) {
#pragma unroll
                for (int r = 0; r < 4; r++) {
                    const int row = 16 + quad * 4 + r;
                    const float v = (kcol <= qb1 + quad * 4 + r) ? z1[r] + kmc : NEGF;
                    const float e = exp2f(v);
                    l_part[1][r] += e;
                    myP[row * 64 + lr7 + (((nf * 2 + lrh) ^ (row & 7)) << 3)] = f2bf_trunc(e);
                }
            } else {
#pragma unroll
                for (int r = 0; r < 4; r++) {
                    const int row = 16 + quad * 4 + r;
                    const float e = exp2f(z1[r] + kmc);
                    l_part[1][r] += e;
                    myP[row * 64 + lr7 + (((nf * 2 + lrh) ^ (row & 7)) << 3)] = f2bf_trunc(e);
                }
            }
        }

        __syncthreads();  // B2: V(kt) drained (K(kt+1) not yet issued -> no false stall)

        if (kt + 1 < hi) {  // prefetch K(kt+1): lands during PV, drained at next B1
            if (cur) { GLDS(kSA, kD0); GLDS(kSB, kD1); }
            else     { GLDS(kSA, kE0); GLDS(kSB, kE1); }
            kSA += 64 * D_DIM;
            kSB += 64 * D_DIM;
        }

        // ---- PV: V fragments read once, used by both subtiles ----
#pragma unroll
        for (int cs = 0; cs < 2; cs++) {
            const int swz = cs ? swz1 : swz0;
            const int poff = (((cs * 4 + quad) ^ lr7) << 3);
            const short8 pf0 = *(const short8*)&myP[lr * 64 + poff];
            const short8 pf1 = *(const short8*)&myP[(16 + lr) * 64 + poff];
#pragma unroll
            for (int j = 0; j < 4; j++) {
                const short8 vfj = *(const short8*)&Vs[((j * 16 + lr) * 8 + swz) * 8];
                o[0][j] = __builtin_amdgcn_mfma_f32_16x16x32_bf16(pf0, vfj, o[0][j], 0, 0, 0);
                o[1][j] = __builtin_amdgcn_mfma_f32_16x16x32_bf16(pf1, vfj, o[1][j], 0, 0, 0);
            }
        }
    }
#undef GLDS

    // ---- epilogue: bf16 O-partials + fp32 l-partials ----
    unsigned short* oP = (sp == 0) ? oP0 : ((sp == 1) ? oP1 : oP2);
#pragma unroll
    for (int s = 0; s < 2; s++) {
        const int qbs = s ? qb1 : qb0;
#pragma unroll
        for (int r = 0; r < 4; r++) {
            float ls = l_part[s][r];
            ls += __shfl_xor(ls, 1);
            ls += __shfl_xor(ls, 2);
            ls += __shfl_xor(ls, 4);
            ls += __shfl_xor(ls, 8);
            const int q = qbs + quad * 4 + r;
            if (lr == 0) lP[sp * (BATCH * NHEAD * S_LEN) + (b * NHEAD + h) * S_LEN + q] = ls;
#pragma unroll
            for (int j = 0; j < 4; j++) {
                oP[(size_t)(b * S_LEN + q) * D_DIM + h * DH + j * 16 + lr] = f2bf(o[s][j][r]);
            }
        }
    }
}

// ---------------- residual + layernorm + split-K combine (up to 3 partials) ------------
__global__ __launch_bounds__(256) void ln_kernel(
    const unsigned short* __restrict__ oP0, const unsigned short* __restrict__ oP1,
    const unsigned short* __restrict__ oP2, const float* __restrict__ lP,
    const float* __restrict__ qmask, const float* __restrict__ queries,
    const float* __restrict__ gamma, const float* __restrict__ beta,
    float* __restrict__ out) {
    const int row = blockIdx.x;
    const int t = threadIdx.x;
    const int b = row >> 11, q = row & 2047;
    const int qt = q >> 7;  // 128-row q-tiles
    const int ns = (qt <= 4) ? 1 : ((qt <= 10) ? 2 : 3);
    const int h = t >> 4;
    const int lidx = (b * NHEAD + h) * S_LEN + q;
    const int LSTRIDE = BATCH * NHEAD * S_LEN;

    float ls = lP[lidx];
    const size_t ri = (size_t)row * 256 + t;
    const ushort4 a0 = ((const ushort4*)oP0)[ri];
    float sx = bf2f(a0.x), sy = bf2f(a0.y), sz = bf2f(a0.z), sw = bf2f(a0.w);
    if (ns > 1) {
        ls += lP[LSTRIDE + lidx];
        const ushort4 a1 = ((const ushort4*)oP1)[ri];
        sx += bf2f(a1.x); sy += bf2f(a1.y); sz += bf2f(a1.z); sw += bf2f(a1.w);
    }
    if (ns > 2) {
        ls += lP[2 * LSTRIDE + lidx];
        const ushort4 a2 = ((const ushort4*)oP2)[ri];
        sx += bf2f(a2.x); sy += bf2f(a2.y); sz += bf2f(a2.z); sw += bf2f(a2.w);
    }
    const float qmr = qmask[row];
    const float inv0 = (ls > 0.f) ? qmr / ls : 0.f;

    const float4 qv = ((const float4*)(queries + (size_t)row * D_DIM))[t];
    float4 x;
    x.x = sx * inv0 + qv.x;
    x.y = sy * inv0 + qv.y;
    x.z = sz * inv0 + qv.z;
    x.w = sw * inv0 + qv.w;

    float s = x.x + x.y + x.z + x.w;
    float sq = x.x * x.x + x.y * x.y + x.z * x.z + x.w * x.w;
    for (int o = 1; o < 64; o <<= 1) { s += __shfl_xor(s, o); sq += __shfl_xor(sq, o); }
    __shared__ float rs[4], rq[4];
    const int w = t >> 6;
    if ((t & 63) == 0) { rs[w] = s; rq[w] = sq; }
    __syncthreads();
    s = rs[0] + rs[1] + rs[2] + rs[3];
    sq = rq[0] + rq[1] + rq[2] + rq[3];
    const float mean = s * (1.0f / 1024.0f);
    float var = (sq - s * mean) * (1.0f / 1023.0f);
    var = fmaxf(var, 0.f);
    const float inv = 1.0f / (sqrtf(var) + 1e-8f);
    const float4 g = ((const float4*)gamma)[t];
    const float4 bb = ((const float4*)beta)[t];
    float4 y;
    y.x = g.x * (x.x - mean) * inv + bb.x;
    y.y = g.y * (x.y - mean) * inv + bb.y;
    y.z = g.z * (x.z - mean) * inv + bb.z;
    y.w = g.w * (x.w - mean) * inv + bb.w;
    ((float4*)(out + (size_t)row * D_DIM))[t] = y;
}

extern "C" void kernel_launch(void* const* d_in, const int* in_sizes, int n_in, void* d_out,
                              int out_size, void* d_ws, size_t ws_size, hipStream_t stream) {
    const float* queries = (const float*)d_in[0];
    const float* keys = (const float*)d_in[1];
    const float* values = (const float*)d_in[2];
    const float* Wq = (const float*)d_in[3];
    const float* bq = (const float*)d_in[4];
    const float* Wk = (const float*)d_in[5];
    const float* bk = (const float*)d_in[6];
    const float* Wv = (const float*)d_in[7];
    const float* bv = (const float*)d_in[8];
    const float* gamma = (const float*)d_in[9];
    const float* beta = (const float*)d_in[10];
    float* out = (float*)d_out;
    char* ws = (char*)d_ws;

    const size_t MB = 1048576;
    unsigned short* qin = (unsigned short*)(ws + 0);
    unsigned short* kin = (unsigned short*)(ws + 8 * MB);
    unsigned short* vin = (unsigned short*)(ws + 16 * MB);
    unsigned short* wqb = (unsigned short*)(ws + 24 * MB);
    unsigned short* wkb = (unsigned short*)(ws + 26 * MB);
    unsigned short* wvb = (unsigned short*)(ws + 28 * MB);
    unsigned short* Qb = (unsigned short*)(ws + 30 * MB);
    unsigned short* Kb = (unsigned short*)(ws + 38 * MB);
    unsigned short* Vb = (unsigned short*)(ws + 46 * MB);
    unsigned short* Vt = (unsigned short*)(ws + 0);          // aliases qin (dead after proj)
    unsigned short* oP0 = (unsigned short*)(ws + 16 * MB);   // aliases vin (dead)
    unsigned short* oP1 = (unsigned short*)(ws + 46 * MB);   // aliases Vb (dead after transpose)
    unsigned short* oP2 = (unsigned short*)(ws + 8 * MB);    // aliases kin (dead)
    float* qm = (float*)(ws + 54 * MB);
    float* km = (float*)(ws + 54 * MB + 16384);
    float* lP = (float*)(ws + 54 * MB + 32768);  // 3 x 65536 fp32 = 768KB

    cvt_all_kernel<<<dim3(NROWS + D_DIM, 3), 256, 0, stream>>>(
        queries, keys, values, Wq, Wk, Wv, qin, kin, vin, wqb, wkb, wvb, qm, km);

    proj_kernel<<<768, 256, 0, stream>>>(
        qin, kin, vin, wqb, wkb, wvb, bq, bk, bv, Qb, Kb, Vb);

    transpose_v<<<dim3(S_LEN / 64, NHEAD, BATCH), 256, 0, stream>>>(Vb, Vt);

    attn_kernel<<<dim3(32, NHEAD, BATCH), 256, 0, stream>>>(Qb, Kb, Vt, km, oP0, oP1, oP2, lP);

    ln_kernel<<<NROWS, 256, 0, stream>>>(oP0, oP1, oP2, lP, qm, queries, gamma, beta, out);
}

// Round 9
// 209.617 us; speedup vs baseline: 1.5409x; 1.0530x over previous
//
#include <hip/hip_runtime.h>

#define S_LEN 2048
#define D_DIM 1024
#define NHEAD 16
#define DH 64
#define BATCH 2
#define NROWS (BATCH * S_LEN)  // 4096
#define QSCALE 0.18033688011112042f  // 0.125 * log2(e): scores land in log2 domain

typedef __attribute__((ext_vector_type(8))) short short8;
typedef __attribute__((ext_vector_type(4))) float f32x4;

static __device__ __forceinline__ unsigned short f2bf(float f) {
    unsigned int u = __builtin_bit_cast(unsigned int, f);
    u += 0x7fffu + ((u >> 16) & 1u);
    return (unsigned short)(u >> 16);
}
static __device__ __forceinline__ float bf2f(unsigned short h) {
    unsigned int u = ((unsigned int)h) << 16;
    return __builtin_bit_cast(float, u);
}
static __device__ __forceinline__ unsigned short f2bf_trunc(float f) {
    return (unsigned short)(__builtin_bit_cast(unsigned int, f) >> 16);
}

// ---------------- fp32 -> bf16 convert (inputs + weights) + fused padding masks --------
__global__ __launch_bounds__(256) void cvt_all_kernel(
    const float* __restrict__ s0, const float* __restrict__ s1, const float* __restrict__ s2,
    const float* __restrict__ w0, const float* __restrict__ w1, const float* __restrict__ w2,
    unsigned short* __restrict__ d0, unsigned short* __restrict__ d1,
    unsigned short* __restrict__ d2, unsigned short* __restrict__ e0,
    unsigned short* __restrict__ e1, unsigned short* __restrict__ e2,
    float* __restrict__ qm, float* __restrict__ km) {
    const int y = blockIdx.y;
    const int row = blockIdx.x;
    const int t = threadIdx.x;
    const float* src;
    unsigned short* dst;
    size_t i;
    if (row < NROWS) {
        src = y == 0 ? s0 : (y == 1 ? s1 : s2);
        dst = y == 0 ? d0 : (y == 1 ? d1 : d2);
        i = (size_t)row * 256 + t;
    } else {
        src = y == 0 ? w0 : (y == 1 ? w1 : w2);
        dst = y == 0 ? e0 : (y == 1 ? e1 : e2);
        i = (size_t)(row - NROWS) * 256 + t;
    }
    float4 v = ((const float4*)src)[i];
    ushort4 o;
    o.x = f2bf(v.x); o.y = f2bf(v.y); o.z = f2bf(v.z); o.w = f2bf(v.w);
    ((ushort4*)dst)[i] = o;
    if (row < NROWS && y < 2) {
        float s = v.x + v.y + v.z + v.w;
        for (int off = 1; off < 64; off <<= 1) s += __shfl_xor(s, off);
        __shared__ float red[4];
        const int w = t >> 6;
        if ((t & 63) == 0) red[w] = s;
        __syncthreads();
        if (t == 0) {
            float tt = red[0] + red[1] + red[2] + red[3];
            if (y == 0)
                qm[row] = (tt != 0.0f) ? 1.0f : 0.0f;
            else
                km[row] = (tt != 0.0f) ? 0.0f : -4294967295.0f;
        }
    }
}

// ---------------- fused QKV projection: O = relu(A @ W^T + b), bf16 MFMA ----------------
// Flat 768-block grid, n-major-mod-8 XCD swizzle. z==0 (Q): output scaled by QSCALE.
__global__ __launch_bounds__(256) void proj_kernel(
    const unsigned short* __restrict__ A0, const unsigned short* __restrict__ A1,
    const unsigned short* __restrict__ A2, const unsigned short* __restrict__ W0,
    const unsigned short* __restrict__ W1, const unsigned short* __restrict__ W2,
    const float* __restrict__ b0, const float* __restrict__ b1, const float* __restrict__ b2,
    unsigned short* __restrict__ O0, unsigned short* __restrict__ O1,
    unsigned short* __restrict__ O2) {
    const int u = blockIdx.x;
    const int n = u / 96;
    const int rem = u % 96;
    const int m = rem / 3;
    const int z = rem % 3;
    const unsigned short* A;
    const unsigned short* W;
    const float* bias;
    unsigned short* O;
    if (z == 0) { A = A0; W = W0; bias = b0; O = O0; }
    else if (z == 1) { A = A1; W = W1; bias = b1; O = O1; }
    else { A = A2; W = W2; bias = b2; O = O2; }

    __shared__ __align__(16) unsigned short Asm[128 * 32];
    __shared__ __align__(16) unsigned short Bsm[128 * 32];

    const int t = threadIdx.x;
    const int w = t >> 6, l = t & 63;
    const int quad = l >> 4, lr = l & 15;
    const int wm = w >> 1, wn = w & 1;
    const int m0 = m * 128, n0 = n * 128;

    f32x4 zero = {0.f, 0.f, 0.f, 0.f};
    f32x4 acc[4][4];
#pragma unroll
    for (int i = 0; i < 4; i++)
#pragma unroll
        for (int j = 0; j < 4; j++) acc[i][j] = zero;

    const int c0 = w * 2, c1 = w * 2 + 1;
    const int ar0 = c0 * 16 + (l >> 2), ar1 = c1 * 16 + (l >> 2);
    const int acol = (l & 3) * 8;

    for (int kt = 0; kt < D_DIM / 32; ++kt) {
        const int k0 = kt * 32;
        __syncthreads();
        __builtin_amdgcn_global_load_lds(
            (const __attribute__((address_space(1))) void*)(A + (size_t)(m0 + ar0) * D_DIM + k0 + acol),
            (__attribute__((address_space(3))) void*)(&Asm[c0 * 512]), 16, 0, 0);
        __builtin_amdgcn_global_load_lds(
            (const __attribute__((address_space(1))) void*)(A + (size_t)(m0 + ar1) * D_DIM + k0 + acol),
            (__attribute__((address_space(3))) void*)(&Asm[c1 * 512]), 16, 0, 0);
        __builtin_amdgcn_global_load_lds(
            (const __attribute__((address_space(1))) void*)(W + (size_t)(n0 + ar0) * D_DIM + k0 + acol),
            (__attribute__((address_space(3))) void*)(&Bsm[c0 * 512]), 16, 0, 0);
        __builtin_amdgcn_global_load_lds(
            (const __attribute__((address_space(1))) void*)(W + (size_t)(n0 + ar1) * D_DIM + k0 + acol),
            (__attribute__((address_space(3))) void*)(&Bsm[c1 * 512]), 16, 0, 0);
        __syncthreads();

        short8 af[4], bf[4];
#pragma unroll
        for (int i = 0; i < 4; i++)
            af[i] = *(const short8*)&Asm[(wm * 64 + i * 16 + lr) * 32 + quad * 8];
#pragma unroll
        for (int j = 0; j < 4; j++)
            bf[j] = *(const short8*)&Bsm[(wn * 64 + j * 16 + lr) * 32 + quad * 8];
#pragma unroll
        for (int i = 0; i < 4; i++)
#pragma unroll
            for (int j = 0; j < 4; j++)
                acc[i][j] = __builtin_amdgcn_mfma_f32_16x16x32_bf16(af[i], bf[j], acc[i][j], 0, 0, 0);
    }

    const float oscale = (z == 0) ? QSCALE : 1.0f;
#pragma unroll
    for (int j = 0; j < 4; j++) {
        const int gn = n0 + wn * 64 + j * 16 + lr;
        const float bj = bias[gn];
#pragma unroll
        for (int i = 0; i < 4; i++) {
            const int gmb = m0 + wm * 64 + i * 16 + quad * 4;
#pragma unroll
            for (int r = 0; r < 4; r++) {
                float v = fmaxf(acc[i][j][r] + bj, 0.f) * oscale;
                O[(size_t)(gmb + r) * D_DIM + gn] = f2bf(v);
            }
        }
    }
}

// ---------------- V transpose: (B,S,D) bf16 -> (B,H,dh,S) bf16 (coalesced both ways) ----
__global__ __launch_bounds__(256) void transpose_v(const unsigned short* __restrict__ Vb,
                                                   unsigned short* __restrict__ Vt) {
    __shared__ unsigned short tile[64][65];
    const int s0 = blockIdx.x * 64, h = blockIdx.y, b = blockIdx.z;
    const int t = threadIdx.x;
#pragma unroll
    for (int p = 0; p < 16; p++) {
        int idx = p * 256 + t;
        int si = idx >> 6, ni = idx & 63;
        tile[si][ni] = Vb[(size_t)(b * S_LEN + s0 + si) * D_DIM + h * DH + ni];
    }
    __syncthreads();
#pragma unroll
    for (int p = 0; p < 16; p++) {
        int idx = p * 256 + t;
        int ni = idx >> 6, si = idx & 63;
        Vt[((size_t)(b * NHEAD + h) * DH + ni) * S_LEN + s0 + si] = tile[si][ni];
    }
}

// ---------------- flash attention: R6 structure + K-prefetch after B2 -------------------
// grid (63, H, B) = 2016 blocks (>=2x co-residency for tail backfill — R8 lesson).
// 64-row q-tiles, wave = 16 q-rows. LDS 32768 B -> 5 blocks/CU.
// B2 drains only V + kmask (latency covered by QK+softmax); K(kt+1) issued AFTER B2 so
// its completion is awaited at the NEXT B1, not at B2 (R6's false drain removed).
__global__ __launch_bounds__(256) void attn_kernel(
    const unsigned short* __restrict__ Qb, const unsigned short* __restrict__ Kb,
    const unsigned short* __restrict__ Vt, const float* __restrict__ km_pen,
    unsigned short* __restrict__ oP0, unsigned short* __restrict__ oP1,
    unsigned short* __restrict__ oP2, float* __restrict__ lP) {
    __shared__ __align__(16) unsigned short Ks[2][64 * 64];
    __shared__ __align__(16) unsigned short Vs[64 * 64];
    __shared__ __align__(16) unsigned short Ps[4][16 * 64];

    const int w = threadIdx.x >> 6, l = threadIdx.x & 63;
    const int quad = l >> 4, lr = l & 15;
    const int h = blockIdx.y, b = blockIdx.z;
    const float NEGF = -4294967295.0f;

    // ---- work assignment (LPT: longest first) ----
    int qt, sp;
    const int x = blockIdx.x;
    int ns;
    if (x < 30) { qt = 31 - x / 3; sp = x % 3; ns = 3; }
    else if (x < 52) { int y = x - 30; qt = 21 - y / 2; sp = y % 2; ns = 2; }
    else { qt = 62 - x; sp = 0; ns = 1; }
    const int T = qt + 1;
    const int lo = sp * T / ns, hi = (sp + 1) * T / ns;

    const int q0 = qt * 64;
    const int qbase = q0 + w * 16;

    const int cA = w * 128 + l;
    const int cB = w * 128 + 64 + l;
    const int keyA = cA >> 3, cbA = (cA & 7) ^ (keyA & 7);
    const int keyB = cB >> 3, cbB = (cB & 7) ^ (keyB & 7);
    const unsigned short* Krow = Kb + (size_t)b * S_LEN * D_DIM + h * DH;
    const unsigned short* Vrow = Vt + (size_t)(b * NHEAD + h) * DH * S_LEN;

    // incremental staging pointers (advance per tile; no per-tile addr recompute)
    const unsigned short* kSA = Krow + (size_t)(lo * 64 + keyA) * D_DIM + cbA * 8;
    const unsigned short* kSB = Krow + (size_t)(lo * 64 + keyB) * D_DIM + cbB * 8;
    const unsigned short* vSA = Vrow + (size_t)keyA * S_LEN + lo * 64 + cbA * 8;
    const unsigned short* vSB = Vrow + (size_t)keyB * S_LEN + lo * 64 + cbB * 8;
    const float* kmp = km_pen + b * S_LEN + lo * 64 + lr;

    unsigned short* const kD0 = &Ks[0][(w * 128) * 8];
    unsigned short* const kD1 = &Ks[0][(w * 128 + 64) * 8];
    unsigned short* const kE0 = &Ks[1][(w * 128) * 8];
    unsigned short* const kE1 = &Ks[1][(w * 128 + 64) * 8];
    unsigned short* const vD0 = &Vs[(w * 128) * 8];
    unsigned short* const vD1 = &Vs[(w * 128 + 64) * 8];

    const unsigned short* qptr = Qb + (size_t)(b * S_LEN + qbase + lr) * D_DIM + h * DH + quad * 8;
    const short8 qf0 = *(const short8*)(qptr);
    const short8 qf1 = *(const short8*)(qptr + 32);

    f32x4 zero = {0.f, 0.f, 0.f, 0.f};
    f32x4 o[4];
#pragma unroll
    for (int j = 0; j < 4; j++) o[j] = zero;
    float l_part[4] = {0.f, 0.f, 0.f, 0.f};

    unsigned short* myP = Ps[w];
    const int swz0 = quad ^ (lr & 7);
    const int swz1 = (quad + 4) ^ (lr & 7);

#define GLDS(src, dst)                                                                  \
    __builtin_amdgcn_global_load_lds((const __attribute__((address_space(1))) void*)(src), \
                                     (__attribute__((address_space(3))) void*)(dst), 16, 0, 0)

    // stage K(lo) into Ks[0]
    GLDS(kSA, kD0);
    GLDS(kSB, kD1);
    kSA += 64 * D_DIM;
    kSB += 64 * D_DIM;

    for (int kt = lo; kt < hi; ++kt) {
        const int cur = (kt - lo) & 1;
        __syncthreads();  // B1: K(kt) staged (drain), prev PV reads of Vs done
        GLDS(vSA, vD0);   // V(kt): lands during QK+softmax, drained at B2
        GLDS(vSB, vD1);
        vSA += 64;
        vSB += 64;

        float kmv[4];
#pragma unroll
        for (int nf = 0; nf < 4; nf++) kmv[nf] = kmp[nf * 16];
        kmp += 64;

        // ---- scores (log2 domain): 16q x 64k ----
        f32x4 sc[4];
#pragma unroll
        for (int nf = 0; nf < 4; nf++) {
            const int key = nf * 16 + lr;
            const short8 kf0 = *(const short8*)&Ks[cur][(key * 8 + swz0) * 8];
            const short8 kf1 = *(const short8*)&Ks[cur][(key * 8 + swz1) * 8];
            f32x4 z = zero;
            z = __builtin_amdgcn_mfma_f32_16x16x32_bf16(qf0, kf0, z, 0, 0, 0);
            z = __builtin_amdgcn_mfma_f32_16x16x32_bf16(qf1, kf1, z, 0, 0, 0);
            sc[nf] = z;
        }

        // ---- softmax: bare exp2 (scores bounded); causal only on diagonal tile ----
        if (kt == qt) {
            const int k0 = kt * 64;
#pragma unroll
            for (int r = 0; r < 4; r++) {
                const int row = quad * 4 + r;
                const int q = qbase + row;
                const float v0 = (k0 + lr <= q) ? sc[0][r] + kmv[0] : NEGF;
                const float v1 = (k0 + 16 + lr <= q) ? sc[1][r] + kmv[1] : NEGF;
                const float v2 = (k0 + 32 + lr <= q) ? sc[2][r] + kmv[2] : NEGF;
                const float v3 = (k0 + 48 + lr <= q) ? sc[3][r] + kmv[3] : NEGF;
                const float e0 = exp2f(v0);
                const float e1 = exp2f(v1);
                const float e2 = exp2f(v2);
                const float e3 = exp2f(v3);
                l_part[r] += (e0 + e1) + (e2 + e3);
                const int rb = (row & 7);
                const int base = row * 64 + (lr & 7);
                myP[base + (((0 + (lr >> 3)) ^ rb) << 3)] = f2bf_trunc(e0);
                myP[base + (((2 + (lr >> 3)) ^ rb) << 3)] = f2bf_trunc(e1);
                myP[base + (((4 + (lr >> 3)) ^ rb) << 3)] = f2bf_trunc(e2);
                myP[base + (((6 + (lr >> 3)) ^ rb) << 3)] = f2bf_trunc(e3);
            }
        } else {
#pragma unroll
            for (int r = 0; r < 4; r++) {
                const int row = quad * 4 + r;
                const float e0 = exp2f(sc[0][r] + kmv[0]);
                const float e1 = exp2f(sc[1][r] + kmv[1]);
                const float e2 = exp2f(sc[2][r] + kmv[2]);
                const float e3 = exp2f(sc[3][r] + kmv[3]);
                l_part[r] += (e0 + e1) + (e2 + e3);
                const int rb = (row & 7);
                const int base = row * 64 + (lr & 7);
                myP[base + (((0 + (lr >> 3)) ^ rb) << 3)] = f2bf_trunc(e0);
                myP[base + (((2 + (lr >> 3)) ^ rb) << 3)] = f2bf_trunc(e1);
                myP[base + (((4 + (lr >> 3)) ^ rb) << 3)] = f2bf_trunc(e2);
                myP[base + (((6 + (lr >> 3)) ^ rb) << 3)] = f2bf_trunc(e3);
            }
        }

        __syncthreads();  // B2: drains V + kmask only (K prefetch not yet issued)

        if (kt + 1 < hi) {  // K(kt+1): issued after B2, awaited at next B1
            if (cur) { GLDS(kSA, kD0); GLDS(kSB, kD1); }
            else     { GLDS(kSA, kE0); GLDS(kSB, kE1); }
            kSA += 64 * D_DIM;
            kSB += 64 * D_DIM;
        }

        // ---- V fragments + P (A-layout) + PV ----
#pragma unroll
        for (int s = 0; s < 2; s++) {
            const int swz = s ? swz1 : swz0;
            const short8 pf = *(const short8*)&myP[lr * 64 + (((s * 4 + quad) ^ (lr & 7)) << 3)];
#pragma unroll
            for (int j = 0; j < 4; j++) {
                const short8 vfj = *(const short8*)&Vs[((j * 16 + lr) * 8 + swz) * 8];
                o[j] = __builtin_amdgcn_mfma_f32_16x16x32_bf16(pf, vfj, o[j], 0, 0, 0);
            }
        }
    }
#undef GLDS

    // ---- epilogue: bf16 O-partials + fp32 l-partials ----
    unsigned short* oP = (sp == 0) ? oP0 : ((sp == 1) ? oP1 : oP2);
#pragma unroll
    for (int r = 0; r < 4; r++) {
        float ls = l_part[r];
        ls += __shfl_xor(ls, 1);
        ls += __shfl_xor(ls, 2);
        ls += __shfl_xor(ls, 4);
        ls += __shfl_xor(ls, 8);
        const int q = qbase + quad * 4 + r;
        if (lr == 0) lP[sp * (BATCH * NHEAD * S_LEN) + (b * NHEAD + h) * S_LEN + q] = ls;
#pragma unroll
        for (int j = 0; j < 4; j++) {
            oP[(size_t)(b * S_LEN + q) * D_DIM + h * DH + j * 16 + lr] = f2bf(o[j][r]);
        }
    }
}

// ---------------- residual + layernorm + split-K combine (up to 3 partials) ------------
__global__ __launch_bounds__(256) void ln_kernel(
    const unsigned short* __restrict__ oP0, const unsigned short* __restrict__ oP1,
    const unsigned short* __restrict__ oP2, const float* __restrict__ lP,
    const float* __restrict__ qmask, const float* __restrict__ queries,
    const float* __restrict__ gamma, const float* __restrict__ beta,
    float* __restrict__ out) {
    const int row = blockIdx.x;
    const int t = threadIdx.x;
    const int b = row >> 11, q = row & 2047;
    const int qt = q >> 6;  // 64-row q-tiles
    const int ns = (qt <= 10) ? 1 : ((qt <= 21) ? 2 : 3);
    const int h = t >> 4;
    const int lidx = (b * NHEAD + h) * S_LEN + q;
    const int LSTRIDE = BATCH * NHEAD * S_LEN;

    float ls = lP[lidx];
    const size_t ri = (size_t)row * 256 + t;
    const ushort4 a0 = ((const ushort4*)oP0)[ri];
    float sx = bf2f(a0.x), sy = bf2f(a0.y), sz = bf2f(a0.z), sw = bf2f(a0.w);
    if (ns > 1) {
        ls += lP[LSTRIDE + lidx];
        const ushort4 a1 = ((const ushort4*)oP1)[ri];
        sx += bf2f(a1.x); sy += bf2f(a1.y); sz += bf2f(a1.z); sw += bf2f(a1.w);
    }
    if (ns > 2) {
        ls += lP[2 * LSTRIDE + lidx];
        const ushort4 a2 = ((const ushort4*)oP2)[ri];
        sx += bf2f(a2.x); sy += bf2f(a2.y); sz += bf2f(a2.z); sw += bf2f(a2.w);
    }
    const float qmr = qmask[row];
    const float inv0 = (ls > 0.f) ? qmr / ls : 0.f;

    const float4 qv = ((const float4*)(queries + (size_t)row * D_DIM))[t];
    float4 x;
    x.x = sx * inv0 + qv.x;
    x.y = sy * inv0 + qv.y;
    x.z = sz * inv0 + qv.z;
    x.w = sw * inv0 + qv.w;

    float s = x.x + x.y + x.z + x.w;
    float sq = x.x * x.x + x.y * x.y + x.z * x.z + x.w * x.w;
    for (int o = 1; o < 64; o <<= 1) { s += __shfl_xor(s, o); sq += __shfl_xor(sq, o); }
    __shared__ float rs[4], rq[4];
    const int w = t >> 6;
    if ((t & 63) == 0) { rs[w] = s; rq[w] = sq; }
    __syncthreads();
    s = rs[0] + rs[1] + rs[2] + rs[3];
    sq = rq[0] + rq[1] + rq[2] + rq[3];
    const float mean = s * (1.0f / 1024.0f);
    float var = (sq - s * mean) * (1.0f / 1023.0f);
    var = fmaxf(var, 0.f);
    const float inv = 1.0f / (sqrtf(var) + 1e-8f);
    const float4 g = ((const float4*)gamma)[t];
    const float4 bb = ((const float4*)beta)[t];
    float4 y;
    y.x = g.x * (x.x - mean) * inv + bb.x;
    y.y = g.y * (x.y - mean) * inv + bb.y;
    y.z = g.z * (x.z - mean) * inv + bb.z;
    y.w = g.w * (x.w - mean) * inv + bb.w;
    ((float4*)(out + (size_t)row * D_DIM))[t] = y;
}

extern "C" void kernel_launch(void* const* d_in, const int* in_sizes, int n_in, void* d_out,
                              int out_size, void* d_ws, size_t ws_size, hipStream_t stream) {
    const float* queries = (const float*)d_in[0];
    const float* keys = (const float*)d_in[1];
    const float* values = (const float*)d_in[2];
    const float* Wq = (const float*)d_in[3];
    const float* bq = (const float*)d_in[4];
    const float* Wk = (const float*)d_in[5];
    const float* bk = (const float*)d_in[6];
    const float* Wv = (const float*)d_in[7];
    const float* bv = (const float*)d_in[8];
    const float* gamma = (const float*)d_in[9];
    const float* beta = (const float*)d_in[10];
    float* out = (float*)d_out;
    char* ws = (char*)d_ws;

    const size_t MB = 1048576;
    unsigned short* qin = (unsigned short*)(ws + 0);
    unsigned short* kin = (unsigned short*)(ws + 8 * MB);
    unsigned short* vin = (unsigned short*)(ws + 16 * MB);
    unsigned short* wqb = (unsigned short*)(ws + 24 * MB);
    unsigned short* wkb = (unsigned short*)(ws + 26 * MB);
    unsigned short* wvb = (unsigned short*)(ws + 28 * MB);
    unsigned short* Qb = (unsigned short*)(ws + 30 * MB);
    unsigned short* Kb = (unsigned short*)(ws + 38 * MB);
    unsigned short* Vb = (unsigned short*)(ws + 46 * MB);
    unsigned short* Vt = (unsigned short*)(ws + 0);          // aliases qin (dead after proj)
    unsigned short* oP0 = (unsigned short*)(ws + 16 * MB);   // aliases vin (dead)
    unsigned short* oP1 = (unsigned short*)(ws + 46 * MB);   // aliases Vb (dead after transpose)
    unsigned short* oP2 = (unsigned short*)(ws + 8 * MB);    // aliases kin (dead)
    float* qm = (float*)(ws + 54 * MB);
    float* km = (float*)(ws + 54 * MB + 16384);
    float* lP = (float*)(ws + 54 * MB + 32768);  // 3 x 65536 fp32 = 768KB

    cvt_all_kernel<<<dim3(NROWS + D_DIM, 3), 256, 0, stream>>>(
        queries, keys, values, Wq, Wk, Wv, qin, kin, vin, wqb, wkb, wvb, qm, km);

    proj_kernel<<<768, 256, 0, stream>>>(
        qin, kin, vin, wqb, wkb, wvb, bq, bk, bv, Qb, Kb, Vb);

    transpose_v<<<dim3(S_LEN / 64, NHEAD, BATCH), 256, 0, stream>>>(Vb, Vt);

    attn_kernel<<<dim3(63, NHEAD, BATCH), 256, 0, stream>>>(Qb, Kb, Vt, km, oP0, oP1, oP2, lP);

    ln_kernel<<<NROWS, 256, 0, stream>>>(oP0, oP1, oP2, lP, qm, queries, gamma, beta, out);
}